// Round 1
// baseline (1027.504 us; speedup 1.0000x reference)
//
#include <hip/hip_runtime.h>
#include <cstddef>
#include <cstdint>

// ---------------------------------------------------------------------------
// JKNet: h1 = relu((D_in^-1/2 * A * D_out^-1/2 * x) @ W1 + b1)
//        h2 = relu((D_in^-1/2 * A * D_out^-1/2 * h1) @ W2 + b2)
//        out = (A @ [h1|h2]) @ Wout + bout
// Strategy: SpMM commutes with dense GEMM -> aggregate first, GEMM after.
//   pass A: aggA[v]  = sum_{e:dst=v} x[src]*invout[src]      ; h1 = relu((aggA@W1)*invin + b1)   (in-place)
//   pass B: acc3[v]  = sum h1[src]; accB[v] = sum h1[src]*invout[src] (one gather, two accums)
//           h2 = relu((accB@W2)*invin + b2)                  (in-place)
//   pass C: acc4[v]  = sum h2[src]
//   out = acc3@Wout[0:128] + acc4@Wout[128:256] + bout
// CSR (by dst) built per launch: histogram -> 2-level scan -> scatter.
// ---------------------------------------------------------------------------

#define THREADS 256

__device__ __forceinline__ float4 f4_fma(const float4 v, const float w, float4 a) {
  a.x += v.x * w; a.y += v.y * w; a.z += v.z * w; a.w += v.w * w; return a;
}
__device__ __forceinline__ float4 f4_add(const float4 v, float4 a) {
  a.x += v.x; a.y += v.y; a.z += v.z; a.w += v.w; return a;
}

// ---- degree histogram ------------------------------------------------------
__global__ void k_degrees(const int* __restrict__ src, const int* __restrict__ dst,
                          int* __restrict__ deg_o, int* __restrict__ deg_i, int E) {
  int i = blockIdx.x * blockDim.x + threadIdx.x;
  int stride = gridDim.x * blockDim.x;
  for (; i < E; i += stride) {
    atomicAdd(&deg_o[src[i]], 1);
    atomicAdd(&deg_i[dst[i]], 1);
  }
}

// ---- inv-sqrt degree -------------------------------------------------------
__global__ void k_inv(const int* __restrict__ deg_o, const int* __restrict__ deg_i,
                      float* __restrict__ inv_out, float* __restrict__ inv_in, int N) {
  int i = blockIdx.x * blockDim.x + threadIdx.x;
  if (i < N) {
    inv_out[i] = rsqrtf((float)max(deg_o[i], 1));
    inv_in[i]  = rsqrtf((float)max(deg_i[i], 1));
  }
}

// ---- exclusive scan of deg_i -> row_ptr (3 kernels, chunk=1024) ------------
__global__ void k_scan1(const int* __restrict__ deg, int* __restrict__ incl,
                        int* __restrict__ bsums, int N) {
  __shared__ int sd[1024];
  int base = blockIdx.x * 1024;
  for (int j = threadIdx.x; j < 1024; j += THREADS) sd[j] = (base + j < N) ? deg[base + j] : 0;
  __syncthreads();
  for (int off = 1; off < 1024; off <<= 1) {
    int v[4];
#pragma unroll
    for (int k = 0; k < 4; ++k) { int j = threadIdx.x + k * THREADS; v[k] = (j >= off) ? sd[j - off] : 0; }
    __syncthreads();
#pragma unroll
    for (int k = 0; k < 4; ++k) { int j = threadIdx.x + k * THREADS; sd[j] += v[k]; }
    __syncthreads();
  }
  for (int j = threadIdx.x; j < 1024; j += THREADS) if (base + j < N) incl[base + j] = sd[j];
  if (threadIdx.x == 0) bsums[blockIdx.x] = sd[1023];
}

__global__ void k_scan2(const int* __restrict__ bsums, int* __restrict__ boffs, int nb) {
  // nb <= 256
  __shared__ int sd[256];
  int t = threadIdx.x;
  sd[t] = (t < nb) ? bsums[t] : 0;
  __syncthreads();
  for (int off = 1; off < 256; off <<= 1) {
    int v = (t >= off) ? sd[t - off] : 0;
    __syncthreads();
    sd[t] += v;
    __syncthreads();
  }
  if (t < nb) boffs[t] = (t == 0) ? 0 : sd[t - 1];
}

__global__ void k_scan3(int* __restrict__ incl_rowptr, const int* __restrict__ deg,
                        const int* __restrict__ boffs, int* __restrict__ cursor,
                        int N, int E) {
  int i = blockIdx.x * blockDim.x + threadIdx.x;
  if (i < N) {
    int excl = incl_rowptr[i] - deg[i] + boffs[i >> 10];
    incl_rowptr[i] = excl;
    cursor[i] = excl;
  }
  if (i == 0) incl_rowptr[N] = E;
}

// ---- scatter edges into CSR buckets ---------------------------------------
__global__ void k_scatter(const int* __restrict__ src, const int* __restrict__ dst,
                          int* __restrict__ cursor, int* __restrict__ csr_src, int E) {
  int i = blockIdx.x * blockDim.x + threadIdx.x;
  int stride = gridDim.x * blockDim.x;
  for (; i < E; i += stride) {
    int d = dst[i];
    int pos = atomicAdd(&cursor[d], 1);
    csr_src[pos] = src[i];
  }
}

// ---- CSR aggregation: 32 lanes per node, float4 per lane -------------------
// MODE 0: O1 = sum v*invout[s]
// MODE 1: O1 = sum v ; O2 = sum v*invout[s]
// MODE 2: O1 = sum v
template <int MODE>
__global__ __launch_bounds__(THREADS)
void k_agg(const float4* __restrict__ H, const float* __restrict__ inv_out,
           const int* __restrict__ row_ptr, const int* __restrict__ csr_src,
           float4* __restrict__ O1, float4* __restrict__ O2, int N) {
  int g = blockIdx.x * (THREADS / 32) + (threadIdx.x >> 5);
  int lane = threadIdx.x & 31;
  if (g >= N) return;
  int e = row_ptr[g], end = row_ptr[g + 1];
  float4 s1 = make_float4(0.f, 0.f, 0.f, 0.f);
  float4 s2 = make_float4(0.f, 0.f, 0.f, 0.f);
  // 2-edge unroll: two independent row loads in flight
  for (; e + 1 < end; e += 2) {
    int n0 = csr_src[e], n1 = csr_src[e + 1];
    float4 v0 = H[(size_t)n0 * 32 + lane];
    float4 v1 = H[(size_t)n1 * 32 + lane];
    if (MODE == 0) {
      float w0 = inv_out[n0], w1 = inv_out[n1];
      s1 = f4_fma(v0, w0, s1); s1 = f4_fma(v1, w1, s1);
    } else if (MODE == 1) {
      float w0 = inv_out[n0], w1 = inv_out[n1];
      s1 = f4_add(v0, s1); s1 = f4_add(v1, s1);
      s2 = f4_fma(v0, w0, s2); s2 = f4_fma(v1, w1, s2);
    } else {
      s1 = f4_add(v0, s1); s1 = f4_add(v1, s1);
    }
  }
  if (e < end) {
    int n0 = csr_src[e];
    float4 v0 = H[(size_t)n0 * 32 + lane];
    if (MODE == 0) {
      s1 = f4_fma(v0, inv_out[n0], s1);
    } else if (MODE == 1) {
      s1 = f4_add(v0, s1);
      s2 = f4_fma(v0, inv_out[n0], s2);
    } else {
      s1 = f4_add(v0, s1);
    }
  }
  O1[(size_t)g * 32 + lane] = s1;
  if (MODE == 1) O2[(size_t)g * 32 + lane] = s2;
}

// ---- 128x128 GEMM, fused scale+bias+relu, in-place safe --------------------
// Out[r][c] = relu( (sum_k A[r][k]*W[k][c]) * scale[r] + bias[c] )
template <bool RELU>
__global__ __launch_bounds__(THREADS)
void k_gemm128(const float* __restrict__ A, const float* __restrict__ W,
               const float* __restrict__ bias, const float* __restrict__ scale,
               float* __restrict__ Out, int N) {
  __shared__ float Ws[128 * 128];     // 64 KB
  __shared__ float As[64][132];       // 33 KB, stride 132 floats = 528B (16B aligned)
  int t = threadIdx.x;
  {
    const float4* Wv = (const float4*)W;
    float4* Wsv = (float4*)Ws;
    for (int i = t; i < 128 * 32; i += THREADS) Wsv[i] = Wv[i];
  }
  int row0 = blockIdx.x * 64;
  for (int i = t; i < 64 * 32; i += THREADS) {
    int r = i >> 5, c4 = i & 31;
    float4 v = make_float4(0.f, 0.f, 0.f, 0.f);
    if (row0 + r < N) v = ((const float4*)A)[(size_t)(row0 + r) * 32 + c4];
    *(float4*)&As[r][c4 * 4] = v;
  }
  __syncthreads();

  int tr4 = (t >> 4) * 4;      // 16 row-groups of 4 rows
  int c0 = (t & 15) * 8;       // 16 col-groups of 8 cols
  float acc[4][8] = {};
#pragma unroll 4
  for (int k = 0; k < 128; ++k) {
    float a0 = As[tr4 + 0][k], a1 = As[tr4 + 1][k], a2 = As[tr4 + 2][k], a3 = As[tr4 + 3][k];
    float4 w0 = *(const float4*)&Ws[k * 128 + c0];
    float4 w1 = *(const float4*)&Ws[k * 128 + c0 + 4];
    float wv[8] = {w0.x, w0.y, w0.z, w0.w, w1.x, w1.y, w1.z, w1.w};
#pragma unroll
    for (int j = 0; j < 8; ++j) {
      acc[0][j] += a0 * wv[j];
      acc[1][j] += a1 * wv[j];
      acc[2][j] += a2 * wv[j];
      acc[3][j] += a3 * wv[j];
    }
  }

  float bj[8];
#pragma unroll
  for (int j = 0; j < 8; ++j) bj[j] = bias[c0 + j];
#pragma unroll
  for (int i = 0; i < 4; ++i) {
    int r = row0 + tr4 + i;
    if (r < N) {
      float s = scale[r];
      float o[8];
#pragma unroll
      for (int j = 0; j < 8; ++j) {
        float v = acc[i][j] * s + bj[j];
        o[j] = RELU ? fmaxf(v, 0.f) : v;
      }
      float4* op = (float4*)Out + (size_t)r * 32 + (c0 >> 2);
      op[0] = make_float4(o[0], o[1], o[2], o[3]);
      op[1] = make_float4(o[4], o[5], o[6], o[7]);
    }
  }
}

// ---- output GEMM: out = A3 @ Wout[0:128] + A4 @ Wout[128:256] + bout -------
__global__ __launch_bounds__(THREADS)
void k_gemm_out(const float* __restrict__ A3, const float* __restrict__ A4,
                const float* __restrict__ Wo, const float* __restrict__ bo,
                float* __restrict__ Out, int N) {
  __shared__ float Ws[256 * 64];      // 64 KB
  __shared__ float As[64][132];       // 33 KB
  int t = threadIdx.x;
  {
    const float4* Wv = (const float4*)Wo;
    float4* Wsv = (float4*)Ws;
    for (int i = t; i < 256 * 16; i += THREADS) Wsv[i] = Wv[i];
  }
  int row0 = blockIdx.x * 64;
  int tr4 = (t >> 4) * 4;
  int c0 = (t & 15) * 4;
  float acc[4][4] = {};
  const float* Aptr[2] = {A3, A4};
  for (int p = 0; p < 2; ++p) {
    __syncthreads();   // p=0: W staged; p=1: previous compute done
    for (int i = t; i < 64 * 32; i += THREADS) {
      int r = i >> 5, c4 = i & 31;
      float4 v = make_float4(0.f, 0.f, 0.f, 0.f);
      if (row0 + r < N) v = ((const float4*)Aptr[p])[(size_t)(row0 + r) * 32 + c4];
      *(float4*)&As[r][c4 * 4] = v;
    }
    __syncthreads();
    int kb = p * 128;
#pragma unroll 4
    for (int k = 0; k < 128; ++k) {
      float a0 = As[tr4 + 0][k], a1 = As[tr4 + 1][k], a2 = As[tr4 + 2][k], a3 = As[tr4 + 3][k];
      float4 w = *(const float4*)&Ws[(kb + k) * 64 + c0];
      float wv[4] = {w.x, w.y, w.z, w.w};
#pragma unroll
      for (int j = 0; j < 4; ++j) {
        acc[0][j] += a0 * wv[j];
        acc[1][j] += a1 * wv[j];
        acc[2][j] += a2 * wv[j];
        acc[3][j] += a3 * wv[j];
      }
    }
  }
  float b4[4];
#pragma unroll
  for (int j = 0; j < 4; ++j) b4[j] = bo[c0 + j];
#pragma unroll
  for (int i = 0; i < 4; ++i) {
    int r = row0 + tr4 + i;
    if (r < N) {
      ((float4*)Out)[(size_t)r * 16 + (c0 >> 2)] =
          make_float4(acc[i][0] + b4[0], acc[i][1] + b4[1], acc[i][2] + b4[2], acc[i][3] + b4[3]);
    }
  }
}

// ---------------------------------------------------------------------------
extern "C" void kernel_launch(void* const* d_in, const int* in_sizes, int n_in,
                              void* d_out, int out_size, void* d_ws, size_t ws_size,
                              hipStream_t stream) {
  const float* x    = (const float*)d_in[0];
  const int*   src  = (const int*)d_in[1];
  const int*   dst  = (const int*)d_in[2];
  const float* W1   = (const float*)d_in[3];
  const float* b1   = (const float*)d_in[4];
  const float* W2   = (const float*)d_in[5];
  const float* b2   = (const float*)d_in[6];
  const float* Wout = (const float*)d_in[7];
  const float* bout = (const float*)d_in[8];
  float* out = (float*)d_out;

  const int IN = 128;
  const int N = in_sizes[0] / IN;   // 100000
  const int E = in_sizes[1];        // 1600000

  // workspace carve-out (all 256B aligned)
  char* p = (char*)d_ws;
  auto alloc = [&](size_t bytes) -> char* {
    char* r = p;
    p += (bytes + 255) & ~(size_t)255;
    return r;
  };
  float* buf1   = (float*)alloc((size_t)N * 128 * 4);  // aggA -> h1 -> acc4
  float* buf2   = (float*)alloc((size_t)N * 128 * 4);  // acc3
  float* buf3   = (float*)alloc((size_t)N * 128 * 4);  // accB -> h2
  float* invo   = (float*)alloc((size_t)N * 4);
  float* invi   = (float*)alloc((size_t)N * 4);
  int* deg_o    = (int*)alloc((size_t)N * 4);
  int* deg_i    = (int*)alloc((size_t)N * 4);
  int* row_ptr  = (int*)alloc((size_t)(N + 1) * 4);    // also used as inclusive-scan temp
  int* cursor   = (int*)alloc((size_t)N * 4);
  int* bsums    = (int*)alloc(1024);
  int* boffs    = (int*)alloc(1024);
  int* csr_src  = (int*)alloc((size_t)E * 4);

  // ---- CSR build -----------------------------------------------------------
  hipMemsetAsync(deg_o, 0, (size_t)N * 4, stream);
  hipMemsetAsync(deg_i, 0, (size_t)N * 4, stream);
  k_degrees<<<2048, THREADS, 0, stream>>>(src, dst, deg_o, deg_i, E);
  k_inv<<<(N + THREADS - 1) / THREADS, THREADS, 0, stream>>>(deg_o, deg_i, invo, invi, N);
  int nb1 = (N + 1023) / 1024;     // 98 (<=256 required by k_scan2)
  k_scan1<<<nb1, THREADS, 0, stream>>>(deg_i, row_ptr, bsums, N);
  k_scan2<<<1, 256, 0, stream>>>(bsums, boffs, nb1);
  k_scan3<<<(N + THREADS - 1) / THREADS, THREADS, 0, stream>>>(row_ptr, deg_i, boffs, cursor, N, E);
  k_scatter<<<2048, THREADS, 0, stream>>>(src, dst, cursor, csr_src, E);

  const int aggGrid = (N + (THREADS / 32) - 1) / (THREADS / 32);
  const int gemmGrid = (N + 63) / 64;

  // ---- layer 1 -------------------------------------------------------------
  k_agg<0><<<aggGrid, THREADS, 0, stream>>>((const float4*)x, invo, row_ptr, csr_src,
                                            (float4*)buf1, nullptr, N);
  k_gemm128<true><<<gemmGrid, THREADS, 0, stream>>>(buf1, W1, b1, invi, buf1, N);  // h1 in buf1

  // ---- layer 2 + JK branch (one gather, two accumulators) ------------------
  k_agg<1><<<aggGrid, THREADS, 0, stream>>>((const float4*)buf1, invo, row_ptr, csr_src,
                                            (float4*)buf2, (float4*)buf3, N);      // buf2=acc3, buf3=accB
  k_gemm128<true><<<gemmGrid, THREADS, 0, stream>>>(buf3, W2, b2, invi, buf3, N);  // h2 in buf3

  // ---- final aggregation of h2 --------------------------------------------
  k_agg<2><<<aggGrid, THREADS, 0, stream>>>((const float4*)buf3, nullptr, row_ptr, csr_src,
                                            (float4*)buf1, nullptr, N);            // acc4 in buf1

  // ---- output GEMM ---------------------------------------------------------
  k_gemm_out<<<gemmGrid, THREADS, 0, stream>>>(buf2, buf1, Wout, bout, out, N);
}

// Round 2
// 898.200 us; speedup vs baseline: 1.1440x; 1.1440x over previous
//
#include <hip/hip_runtime.h>
#include <cstddef>
#include <cstdint>

// ---------------------------------------------------------------------------
// JKNet: h1 = relu((D_in^-1/2 * A * D_out^-1/2 * x) @ W1 + b1)
//        h2 = relu((D_in^-1/2 * A * D_out^-1/2 * h1) @ W2 + b2)
//        out = (A @ [h1|h2]) @ Wout + bout
// Aggregate-first refactor (SpMM commutes with dense GEMM); CSR built per
// launch (histogram -> scan -> scatter).
// R1: GEMMs restructured for occupancy: K-chunked (kc=32) double-buffered LDS,
//     transposed A-tile (b128 LDS reads), async reg-staged prefetch.
//     gemm128: 128x128 tile, 8x8/thread, 65KB LDS -> 2 blocks/CU.
//     gemm_out: 128x64 tile, 8x4/thread, 49KB LDS -> 3 blocks/CU.
// ---------------------------------------------------------------------------

#define THREADS 256

__device__ __forceinline__ float4 f4_fma(const float4 v, const float w, float4 a) {
  a.x += v.x * w; a.y += v.y * w; a.z += v.z * w; a.w += v.w * w; return a;
}
__device__ __forceinline__ float4 f4_add(const float4 v, float4 a) {
  a.x += v.x; a.y += v.y; a.z += v.z; a.w += v.w; return a;
}

// ---- degree histogram ------------------------------------------------------
__global__ void k_degrees(const int* __restrict__ src, const int* __restrict__ dst,
                          int* __restrict__ deg_o, int* __restrict__ deg_i, int E) {
  int i = blockIdx.x * blockDim.x + threadIdx.x;
  int stride = gridDim.x * blockDim.x;
  for (; i < E; i += stride) {
    atomicAdd(&deg_o[src[i]], 1);
    atomicAdd(&deg_i[dst[i]], 1);
  }
}

// ---- inv-sqrt degree -------------------------------------------------------
__global__ void k_inv(const int* __restrict__ deg_o, const int* __restrict__ deg_i,
                      float* __restrict__ inv_out, float* __restrict__ inv_in, int N) {
  int i = blockIdx.x * blockDim.x + threadIdx.x;
  if (i < N) {
    inv_out[i] = rsqrtf((float)max(deg_o[i], 1));
    inv_in[i]  = rsqrtf((float)max(deg_i[i], 1));
  }
}

// ---- exclusive scan of deg_i -> row_ptr (3 kernels, chunk=1024) ------------
__global__ void k_scan1(const int* __restrict__ deg, int* __restrict__ incl,
                        int* __restrict__ bsums, int N) {
  __shared__ int sd[1024];
  int base = blockIdx.x * 1024;
  for (int j = threadIdx.x; j < 1024; j += THREADS) sd[j] = (base + j < N) ? deg[base + j] : 0;
  __syncthreads();
  for (int off = 1; off < 1024; off <<= 1) {
    int v[4];
#pragma unroll
    for (int k = 0; k < 4; ++k) { int j = threadIdx.x + k * THREADS; v[k] = (j >= off) ? sd[j - off] : 0; }
    __syncthreads();
#pragma unroll
    for (int k = 0; k < 4; ++k) { int j = threadIdx.x + k * THREADS; sd[j] += v[k]; }
    __syncthreads();
  }
  for (int j = threadIdx.x; j < 1024; j += THREADS) if (base + j < N) incl[base + j] = sd[j];
  if (threadIdx.x == 0) bsums[blockIdx.x] = sd[1023];
}

__global__ void k_scan2(const int* __restrict__ bsums, int* __restrict__ boffs, int nb) {
  __shared__ int sd[256];
  int t = threadIdx.x;
  sd[t] = (t < nb) ? bsums[t] : 0;
  __syncthreads();
  for (int off = 1; off < 256; off <<= 1) {
    int v = (t >= off) ? sd[t - off] : 0;
    __syncthreads();
    sd[t] += v;
    __syncthreads();
  }
  if (t < nb) boffs[t] = (t == 0) ? 0 : sd[t - 1];
}

__global__ void k_scan3(int* __restrict__ incl_rowptr, const int* __restrict__ deg,
                        const int* __restrict__ boffs, int* __restrict__ cursor,
                        int N, int E) {
  int i = blockIdx.x * blockDim.x + threadIdx.x;
  if (i < N) {
    int excl = incl_rowptr[i] - deg[i] + boffs[i >> 10];
    incl_rowptr[i] = excl;
    cursor[i] = excl;
  }
  if (i == 0) incl_rowptr[N] = E;
}

// ---- scatter edges into CSR buckets ---------------------------------------
__global__ void k_scatter(const int* __restrict__ src, const int* __restrict__ dst,
                          int* __restrict__ cursor, int* __restrict__ csr_src, int E) {
  int i = blockIdx.x * blockDim.x + threadIdx.x;
  int stride = gridDim.x * blockDim.x;
  for (; i < E; i += stride) {
    int d = dst[i];
    int pos = atomicAdd(&cursor[d], 1);
    csr_src[pos] = src[i];
  }
}

// ---- CSR aggregation: 32 lanes per node, float4 per lane -------------------
// MODE 0: O1 = sum v*invout[s]
// MODE 1: O1 = sum v ; O2 = sum v*invout[s]
// MODE 2: O1 = sum v
template <int MODE>
__global__ __launch_bounds__(THREADS)
void k_agg(const float4* __restrict__ H, const float* __restrict__ inv_out,
           const int* __restrict__ row_ptr, const int* __restrict__ csr_src,
           float4* __restrict__ O1, float4* __restrict__ O2, int N) {
  int g = blockIdx.x * (THREADS / 32) + (threadIdx.x >> 5);
  int lane = threadIdx.x & 31;
  if (g >= N) return;
  int e = row_ptr[g], end = row_ptr[g + 1];
  float4 s1 = make_float4(0.f, 0.f, 0.f, 0.f);
  float4 s2 = make_float4(0.f, 0.f, 0.f, 0.f);
  for (; e + 1 < end; e += 2) {
    int n0 = csr_src[e], n1 = csr_src[e + 1];
    float4 v0 = H[(size_t)n0 * 32 + lane];
    float4 v1 = H[(size_t)n1 * 32 + lane];
    if (MODE == 0) {
      float w0 = inv_out[n0], w1 = inv_out[n1];
      s1 = f4_fma(v0, w0, s1); s1 = f4_fma(v1, w1, s1);
    } else if (MODE == 1) {
      float w0 = inv_out[n0], w1 = inv_out[n1];
      s1 = f4_add(v0, s1); s1 = f4_add(v1, s1);
      s2 = f4_fma(v0, w0, s2); s2 = f4_fma(v1, w1, s2);
    } else {
      s1 = f4_add(v0, s1); s1 = f4_add(v1, s1);
    }
  }
  if (e < end) {
    int n0 = csr_src[e];
    float4 v0 = H[(size_t)n0 * 32 + lane];
    if (MODE == 0) {
      s1 = f4_fma(v0, inv_out[n0], s1);
    } else if (MODE == 1) {
      s1 = f4_add(v0, s1);
      s2 = f4_fma(v0, inv_out[n0], s2);
    } else {
      s1 = f4_add(v0, s1);
    }
  }
  O1[(size_t)g * 32 + lane] = s1;
  if (MODE == 1) O2[(size_t)g * 32 + lane] = s2;
}

// ---- 128x128 GEMM, fused scale+bias+relu ----------------------------------
// Out[r][c] = relu( (sum_k A[r][k]*W[k][c]) * scale[r] + bias[c] )
// 128-row x 128-col tile, 8x8 per thread, K chunked by 32, double-buffered.
template <bool RELU>
__global__ __launch_bounds__(THREADS, 2)
void k_gemm128(const float* __restrict__ A, const float* __restrict__ W,
               const float* __restrict__ bias, const float* __restrict__ scale,
               float* __restrict__ Out, int N) {
  __shared__ float As[2][32 * 132];   // transposed: As[k][row], stride 132 (16B aligned)
  __shared__ float Ws[2][32 * 128];   // Ws[k][col]
  int t = threadIdx.x;
  int row0 = blockIdx.x * 128;
  int tx = t & 15, ty = t >> 4;
  int c0 = tx * 8, r0 = ty * 8;

  const float4* Av = (const float4*)A;
  const float4* Wv = (const float4*)W;

  float4 la[4], lw[4];
  auto stage_load = [&](int chunk) {
#pragma unroll
    for (int j = 0; j < 4; ++j) {
      int i = t + j * 256;            // 0..1023
      int r = i >> 3, kq = i & 7;     // r: 0..127, kq: float4 within 32-k chunk
      la[j] = make_float4(0.f, 0.f, 0.f, 0.f);
      int gr = row0 + r;
      if (gr < N) la[j] = Av[(size_t)gr * 32 + chunk * 8 + kq];
    }
#pragma unroll
    for (int j = 0; j < 4; ++j) {
      int i = t + j * 256;            // k=i>>5 (0..31), cq=i&31
      lw[j] = Wv[(size_t)(chunk * 32 + (i >> 5)) * 32 + (i & 31)];
    }
  };
  auto stage_write = [&](int buf) {
#pragma unroll
    for (int j = 0; j < 4; ++j) {
      int i = t + j * 256;
      int r = i >> 3, kq = i & 7;
      float* p = As[buf] + kq * 4 * 132 + r;
      p[0] = la[j].x; p[132] = la[j].y; p[264] = la[j].z; p[396] = la[j].w;
    }
    float4* Wsv = (float4*)Ws[buf];
#pragma unroll
    for (int j = 0; j < 4; ++j) Wsv[t + j * 256] = lw[j];
  };

  float acc[8][8] = {};
  stage_load(0);
  stage_write(0);
#pragma unroll 1
  for (int c = 0; c < 4; ++c) {
    __syncthreads();                      // buf[c&1] visible
    if (c < 3) stage_load(c + 1);         // issue next-chunk loads early
    const float* At = As[c & 1];
    const float* Wc = Ws[c & 1];
#pragma unroll 4
    for (int k = 0; k < 32; ++k) {
      float4 a0 = *(const float4*)&At[k * 132 + r0];
      float4 a1 = *(const float4*)&At[k * 132 + r0 + 4];
      float4 w0 = *(const float4*)&Wc[k * 128 + c0];
      float4 w1 = *(const float4*)&Wc[k * 128 + c0 + 4];
      float av[8] = {a0.x, a0.y, a0.z, a0.w, a1.x, a1.y, a1.z, a1.w};
      float wv[8] = {w0.x, w0.y, w0.z, w0.w, w1.x, w1.y, w1.z, w1.w};
#pragma unroll
      for (int ii = 0; ii < 8; ++ii)
#pragma unroll
        for (int jj = 0; jj < 8; ++jj)
          acc[ii][jj] += av[ii] * wv[jj];
    }
    if (c < 3) stage_write((c + 1) & 1);  // loads arrived under compute
  }

  float bj[8];
#pragma unroll
  for (int j = 0; j < 8; ++j) bj[j] = bias[c0 + j];
#pragma unroll
  for (int i = 0; i < 8; ++i) {
    int r = row0 + r0 + i;
    if (r < N) {
      float s = scale[r];
      float o[8];
#pragma unroll
      for (int j = 0; j < 8; ++j) {
        float v = acc[i][j] * s + bj[j];
        o[j] = RELU ? fmaxf(v, 0.f) : v;
      }
      float4* op = (float4*)Out + (size_t)r * 32 + (c0 >> 2);
      op[0] = make_float4(o[0], o[1], o[2], o[3]);
      op[1] = make_float4(o[4], o[5], o[6], o[7]);
    }
  }
}

// ---- output GEMM: out = A3 @ Wo[0:128] + A4 @ Wo[128:256] + bout -----------
// 128-row x 64-col tile, 8x4 per thread, 8 K-chunks of 32 (A3 then A4).
__global__ __launch_bounds__(THREADS, 3)
void k_gemm_out(const float* __restrict__ A3, const float* __restrict__ A4,
                const float* __restrict__ Wo, const float* __restrict__ bo,
                float* __restrict__ Out, int N) {
  __shared__ float As[2][32 * 132];   // As[k][row]
  __shared__ float Ws[2][32 * 64];    // Ws[k][col]
  int t = threadIdx.x;
  int row0 = blockIdx.x * 128;
  int tx = t & 15, ty = t >> 4;
  int c0 = tx * 4, r0 = ty * 8;

  const float4* Wv = (const float4*)Wo;

  float4 la[4], lw[2];
  auto stage_load = [&](int chunk) {
    const float4* Av = (const float4*)((chunk < 4) ? A3 : A4);
    int kb = (chunk & 3) * 8;           // float4 base within row
#pragma unroll
    for (int j = 0; j < 4; ++j) {
      int i = t + j * 256;
      int r = i >> 3, kq = i & 7;
      la[j] = make_float4(0.f, 0.f, 0.f, 0.f);
      int gr = row0 + r;
      if (gr < N) la[j] = Av[(size_t)gr * 32 + kb + kq];
    }
#pragma unroll
    for (int j = 0; j < 2; ++j) {
      int i = t + j * 256;              // k=i>>4 (0..31), cq=i&15
      lw[j] = Wv[(size_t)(chunk * 32 + (i >> 4)) * 16 + (i & 15)];
    }
  };
  auto stage_write = [&](int buf) {
#pragma unroll
    for (int j = 0; j < 4; ++j) {
      int i = t + j * 256;
      int r = i >> 3, kq = i & 7;
      float* p = As[buf] + kq * 4 * 132 + r;
      p[0] = la[j].x; p[132] = la[j].y; p[264] = la[j].z; p[396] = la[j].w;
    }
    float4* Wsv = (float4*)Ws[buf];
#pragma unroll
    for (int j = 0; j < 2; ++j) Wsv[t + j * 256] = lw[j];
  };

  float acc[8][4] = {};
  stage_load(0);
  stage_write(0);
#pragma unroll 1
  for (int c = 0; c < 8; ++c) {
    __syncthreads();
    if (c < 7) stage_load(c + 1);
    const float* At = As[c & 1];
    const float* Wc = Ws[c & 1];
#pragma unroll 4
    for (int k = 0; k < 32; ++k) {
      float4 a0 = *(const float4*)&At[k * 132 + r0];
      float4 a1 = *(const float4*)&At[k * 132 + r0 + 4];
      float4 w = *(const float4*)&Wc[k * 64 + c0];
      float av[8] = {a0.x, a0.y, a0.z, a0.w, a1.x, a1.y, a1.z, a1.w};
      float wv[4] = {w.x, w.y, w.z, w.w};
#pragma unroll
      for (int ii = 0; ii < 8; ++ii)
#pragma unroll
        for (int jj = 0; jj < 4; ++jj)
          acc[ii][jj] += av[ii] * wv[jj];
    }
    if (c < 7) stage_write((c + 1) & 1);
  }

  float b4[4];
#pragma unroll
  for (int j = 0; j < 4; ++j) b4[j] = bo[c0 + j];
#pragma unroll
  for (int i = 0; i < 8; ++i) {
    int r = row0 + r0 + i;
    if (r < N) {
      ((float4*)Out)[(size_t)r * 16 + (c0 >> 2)] =
          make_float4(acc[i][0] + b4[0], acc[i][1] + b4[1],
                      acc[i][2] + b4[2], acc[i][3] + b4[3]);
    }
  }
}

// ---------------------------------------------------------------------------
extern "C" void kernel_launch(void* const* d_in, const int* in_sizes, int n_in,
                              void* d_out, int out_size, void* d_ws, size_t ws_size,
                              hipStream_t stream) {
  const float* x    = (const float*)d_in[0];
  const int*   src  = (const int*)d_in[1];
  const int*   dst  = (const int*)d_in[2];
  const float* W1   = (const float*)d_in[3];
  const float* b1   = (const float*)d_in[4];
  const float* W2   = (const float*)d_in[5];
  const float* b2   = (const float*)d_in[6];
  const float* Wout = (const float*)d_in[7];
  const float* bout = (const float*)d_in[8];
  float* out = (float*)d_out;

  const int IN = 128;
  const int N = in_sizes[0] / IN;   // 100000
  const int E = in_sizes[1];        // 1600000

  char* p = (char*)d_ws;
  auto alloc = [&](size_t bytes) -> char* {
    char* r = p;
    p += (bytes + 255) & ~(size_t)255;
    return r;
  };
  float* buf1   = (float*)alloc((size_t)N * 128 * 4);  // aggA -> h1 -> acc4
  float* buf2   = (float*)alloc((size_t)N * 128 * 4);  // acc3
  float* buf3   = (float*)alloc((size_t)N * 128 * 4);  // accB -> h2
  float* invo   = (float*)alloc((size_t)N * 4);
  float* invi   = (float*)alloc((size_t)N * 4);
  int* deg_o    = (int*)alloc((size_t)N * 4);
  int* deg_i    = (int*)alloc((size_t)N * 4);
  int* row_ptr  = (int*)alloc((size_t)(N + 1) * 4);
  int* cursor   = (int*)alloc((size_t)N * 4);
  int* bsums    = (int*)alloc(1024);
  int* boffs    = (int*)alloc(1024);
  int* csr_src  = (int*)alloc((size_t)E * 4);

  // ---- CSR build -----------------------------------------------------------
  hipMemsetAsync(deg_o, 0, (size_t)N * 4, stream);
  hipMemsetAsync(deg_i, 0, (size_t)N * 4, stream);
  k_degrees<<<2048, THREADS, 0, stream>>>(src, dst, deg_o, deg_i, E);
  k_inv<<<(N + THREADS - 1) / THREADS, THREADS, 0, stream>>>(deg_o, deg_i, invo, invi, N);
  int nb1 = (N + 1023) / 1024;     // 98 (<=256 required by k_scan2)
  k_scan1<<<nb1, THREADS, 0, stream>>>(deg_i, row_ptr, bsums, N);
  k_scan2<<<1, 256, 0, stream>>>(bsums, boffs, nb1);
  k_scan3<<<(N + THREADS - 1) / THREADS, THREADS, 0, stream>>>(row_ptr, deg_i, boffs, cursor, N, E);
  k_scatter<<<2048, THREADS, 0, stream>>>(src, dst, cursor, csr_src, E);

  const int aggGrid = (N + (THREADS / 32) - 1) / (THREADS / 32);
  const int gemmGrid = (N + 127) / 128;

  // ---- layer 1 -------------------------------------------------------------
  k_agg<0><<<aggGrid, THREADS, 0, stream>>>((const float4*)x, invo, row_ptr, csr_src,
                                            (float4*)buf1, nullptr, N);
  k_gemm128<true><<<gemmGrid, THREADS, 0, stream>>>(buf1, W1, b1, invi, buf1, N);  // h1 in buf1

  // ---- layer 2 + JK branch (one gather, two accumulators) ------------------
  k_agg<1><<<aggGrid, THREADS, 0, stream>>>((const float4*)buf1, invo, row_ptr, csr_src,
                                            (float4*)buf2, (float4*)buf3, N);      // buf2=acc3, buf3=accB
  k_gemm128<true><<<gemmGrid, THREADS, 0, stream>>>(buf3, W2, b2, invi, buf3, N);  // h2 in buf3

  // ---- final aggregation of h2 --------------------------------------------
  k_agg<2><<<aggGrid, THREADS, 0, stream>>>((const float4*)buf3, nullptr, row_ptr, csr_src,
                                            (float4*)buf1, nullptr, N);            // acc4 in buf1

  // ---- output GEMM ---------------------------------------------------------
  k_gemm_out<<<gemmGrid, THREADS, 0, stream>>>(buf2, buf1, Wout, bout, out, N);
}

// Round 3
// 795.798 us; speedup vs baseline: 1.2912x; 1.1287x over previous
//
#include <hip/hip_runtime.h>
#include <cstddef>
#include <cstdint>

// ---------------------------------------------------------------------------
// JKNet: h1 = relu((D_in^-1/2 A D_out^-1/2 x) @ W1 + b1)
//        h2 = relu((D_in^-1/2 A D_out^-1/2 h1) @ W2 + b2)
//        out = (A @ [h1|h2]) @ Wout + bout
// Aggregate-first refactor (SpMM commutes with dense GEMM).
// R2a: out = A@(h1@Wo1 + h2@Wo2) -> one 64-wide gather instead of two
//      128-wide accumulator paths. z = h1@Wo1+h2@Wo2 computed densely.
// R2b: XCD-sliced CSR build: blocks in slice-group (blockIdx%8) only touch
//      nodes in their 1/8 range -> csr_src/deg slices stay resident in that
//      XCD's private L2 -> random 4B stores coalesce in-cache (fixes the
//      16x WRITE_SIZE inflation seen in R1: 107MB for a 6.4MB payload).
// ---------------------------------------------------------------------------

#define THREADS 256
#define NSLICE 8

__device__ __forceinline__ float4 f4_fma(const float4 v, const float w, float4 a) {
  a.x += v.x * w; a.y += v.y * w; a.z += v.z * w; a.w += v.w * w; return a;
}
__device__ __forceinline__ float4 f4_add(const float4 v, float4 a) {
  a.x += v.x; a.y += v.y; a.z += v.z; a.w += v.w; return a;
}

// ---- degree histogram, XCD-sliced -----------------------------------------
__global__ void k_degrees(const int* __restrict__ src, const int* __restrict__ dst,
                          int* __restrict__ deg_o, int* __restrict__ deg_i,
                          int N, int E) {
  int slice = blockIdx.x & (NSLICE - 1);
  int sub = blockIdx.x >> 3;
  int nsub = gridDim.x >> 3;
  int lo = (int)(((long long)slice * N) / NSLICE);
  int hi = (int)(((long long)(slice + 1) * N) / NSLICE);
  for (int i = sub * blockDim.x + threadIdx.x; i < E; i += nsub * blockDim.x) {
    int s = src[i];
    int d = dst[i];
    if (s >= lo && s < hi) atomicAdd(&deg_o[s], 1);
    if (d >= lo && d < hi) atomicAdd(&deg_i[d], 1);
  }
}

// ---- inv-sqrt degree -------------------------------------------------------
__global__ void k_inv(const int* __restrict__ deg_o, const int* __restrict__ deg_i,
                      float* __restrict__ inv_out, float* __restrict__ inv_in, int N) {
  int i = blockIdx.x * blockDim.x + threadIdx.x;
  if (i < N) {
    inv_out[i] = rsqrtf((float)max(deg_o[i], 1));
    inv_in[i]  = rsqrtf((float)max(deg_i[i], 1));
  }
}

// ---- exclusive scan of deg_i -> row_ptr (3 kernels, chunk=1024) ------------
__global__ void k_scan1(const int* __restrict__ deg, int* __restrict__ incl,
                        int* __restrict__ bsums, int N) {
  __shared__ int sd[1024];
  int base = blockIdx.x * 1024;
  for (int j = threadIdx.x; j < 1024; j += THREADS) sd[j] = (base + j < N) ? deg[base + j] : 0;
  __syncthreads();
  for (int off = 1; off < 1024; off <<= 1) {
    int v[4];
#pragma unroll
    for (int k = 0; k < 4; ++k) { int j = threadIdx.x + k * THREADS; v[k] = (j >= off) ? sd[j - off] : 0; }
    __syncthreads();
#pragma unroll
    for (int k = 0; k < 4; ++k) { int j = threadIdx.x + k * THREADS; sd[j] += v[k]; }
    __syncthreads();
  }
  for (int j = threadIdx.x; j < 1024; j += THREADS) if (base + j < N) incl[base + j] = sd[j];
  if (threadIdx.x == 0) bsums[blockIdx.x] = sd[1023];
}

__global__ void k_scan2(const int* __restrict__ bsums, int* __restrict__ boffs, int nb) {
  __shared__ int sd[256];
  int t = threadIdx.x;
  sd[t] = (t < nb) ? bsums[t] : 0;
  __syncthreads();
  for (int off = 1; off < 256; off <<= 1) {
    int v = (t >= off) ? sd[t - off] : 0;
    __syncthreads();
    sd[t] += v;
    __syncthreads();
  }
  if (t < nb) boffs[t] = (t == 0) ? 0 : sd[t - 1];
}

__global__ void k_scan3(int* __restrict__ incl_rowptr, const int* __restrict__ deg,
                        const int* __restrict__ boffs, int* __restrict__ cursor,
                        int N, int E) {
  int i = blockIdx.x * blockDim.x + threadIdx.x;
  if (i < N) {
    int excl = incl_rowptr[i] - deg[i] + boffs[i >> 10];
    incl_rowptr[i] = excl;
    cursor[i] = excl;
  }
  if (i == 0) incl_rowptr[N] = E;
}

// ---- scatter edges into CSR buckets, XCD-sliced ----------------------------
__global__ void k_scatter(const int* __restrict__ src, const int* __restrict__ dst,
                          int* __restrict__ cursor, int* __restrict__ csr_src,
                          int N, int E) {
  int slice = blockIdx.x & (NSLICE - 1);
  int sub = blockIdx.x >> 3;
  int nsub = gridDim.x >> 3;
  int lo = (int)(((long long)slice * N) / NSLICE);
  int hi = (int)(((long long)(slice + 1) * N) / NSLICE);
  for (int i = sub * blockDim.x + threadIdx.x; i < E; i += nsub * blockDim.x) {
    int d = dst[i];
    if (d >= lo && d < hi) {
      int pos = atomicAdd(&cursor[d], 1);
      csr_src[pos] = src[i];
    }
  }
}

// ---- CSR aggregation (128-wide): O1[v] = sum_{e:dst=v} H[src]*invout[src] --
__global__ __launch_bounds__(THREADS)
void k_agg(const float4* __restrict__ H, const float* __restrict__ inv_out,
           const int* __restrict__ row_ptr, const int* __restrict__ csr_src,
           float4* __restrict__ O1, int N) {
  int g = blockIdx.x * (THREADS / 32) + (threadIdx.x >> 5);
  int lane = threadIdx.x & 31;
  if (g >= N) return;
  int e = row_ptr[g], end = row_ptr[g + 1];
  float4 s1 = make_float4(0.f, 0.f, 0.f, 0.f);
  for (; e + 1 < end; e += 2) {
    int n0 = csr_src[e], n1 = csr_src[e + 1];
    float4 v0 = H[(size_t)n0 * 32 + lane];
    float4 v1 = H[(size_t)n1 * 32 + lane];
    float w0 = inv_out[n0], w1 = inv_out[n1];
    s1 = f4_fma(v0, w0, s1); s1 = f4_fma(v1, w1, s1);
  }
  if (e < end) {
    int n0 = csr_src[e];
    s1 = f4_fma(H[(size_t)n0 * 32 + lane], inv_out[n0], s1);
  }
  O1[(size_t)g * 32 + lane] = s1;
}

// ---- CSR aggregation (64-wide, unweighted, +bout): out = sum z[src] + bout -
__global__ __launch_bounds__(THREADS)
void k_agg_z(const float4* __restrict__ Z, const int* __restrict__ row_ptr,
             const int* __restrict__ csr_src, const float* __restrict__ bo,
             float4* __restrict__ Out, int N) {
  int g = blockIdx.x * (THREADS / 16) + (threadIdx.x >> 4);
  int lane = threadIdx.x & 15;
  if (g >= N) return;
  int e = row_ptr[g], end = row_ptr[g + 1];
  float4 s = ((const float4*)bo)[lane];
  for (; e + 1 < end; e += 2) {
    int n0 = csr_src[e], n1 = csr_src[e + 1];
    float4 v0 = Z[(size_t)n0 * 16 + lane];
    float4 v1 = Z[(size_t)n1 * 16 + lane];
    s = f4_add(v0, s); s = f4_add(v1, s);
  }
  if (e < end) s = f4_add(Z[(size_t)csr_src[e] * 16 + lane], s);
  Out[(size_t)g * 16 + lane] = s;
}

// ---- 128x128 GEMM, fused scale+bias+relu ----------------------------------
// Out[r][c] = relu( (sum_k A[r][k]*W[k][c]) * scale[r] + bias[c] )
// 128x128 tile, 8x8/thread, K chunked by 32, double-buffered, in-place safe.
template <bool RELU>
__global__ __launch_bounds__(THREADS, 2)
void k_gemm128(const float* __restrict__ A, const float* __restrict__ W,
               const float* __restrict__ bias, const float* __restrict__ scale,
               float* __restrict__ Out, int N) {
  __shared__ float As[2][32 * 132];   // transposed: As[k][row], stride 132
  __shared__ float Ws[2][32 * 128];   // Ws[k][col]
  int t = threadIdx.x;
  int row0 = blockIdx.x * 128;
  int tx = t & 15, ty = t >> 4;
  int c0 = tx * 8, r0 = ty * 8;

  const float4* Av = (const float4*)A;
  const float4* Wv = (const float4*)W;

  float4 la[4], lw[4];
  auto stage_load = [&](int chunk) {
#pragma unroll
    for (int j = 0; j < 4; ++j) {
      int i = t + j * 256;
      int r = i >> 3, kq = i & 7;
      la[j] = make_float4(0.f, 0.f, 0.f, 0.f);
      int gr = row0 + r;
      if (gr < N) la[j] = Av[(size_t)gr * 32 + chunk * 8 + kq];
    }
#pragma unroll
    for (int j = 0; j < 4; ++j) {
      int i = t + j * 256;
      lw[j] = Wv[(size_t)(chunk * 32 + (i >> 5)) * 32 + (i & 31)];
    }
  };
  auto stage_write = [&](int buf) {
#pragma unroll
    for (int j = 0; j < 4; ++j) {
      int i = t + j * 256;
      int r = i >> 3, kq = i & 7;
      float* p = As[buf] + kq * 4 * 132 + r;
      p[0] = la[j].x; p[132] = la[j].y; p[264] = la[j].z; p[396] = la[j].w;
    }
    float4* Wsv = (float4*)Ws[buf];
#pragma unroll
    for (int j = 0; j < 4; ++j) Wsv[t + j * 256] = lw[j];
  };

  float acc[8][8] = {};
  stage_load(0);
  stage_write(0);
#pragma unroll 1
  for (int c = 0; c < 4; ++c) {
    __syncthreads();
    if (c < 3) stage_load(c + 1);
    const float* At = As[c & 1];
    const float* Wc = Ws[c & 1];
#pragma unroll 4
    for (int k = 0; k < 32; ++k) {
      float4 a0 = *(const float4*)&At[k * 132 + r0];
      float4 a1 = *(const float4*)&At[k * 132 + r0 + 4];
      float4 w0 = *(const float4*)&Wc[k * 128 + c0];
      float4 w1 = *(const float4*)&Wc[k * 128 + c0 + 4];
      float av[8] = {a0.x, a0.y, a0.z, a0.w, a1.x, a1.y, a1.z, a1.w};
      float wv[8] = {w0.x, w0.y, w0.z, w0.w, w1.x, w1.y, w1.z, w1.w};
#pragma unroll
      for (int ii = 0; ii < 8; ++ii)
#pragma unroll
        for (int jj = 0; jj < 8; ++jj)
          acc[ii][jj] += av[ii] * wv[jj];
    }
    if (c < 3) stage_write((c + 1) & 1);
  }

  float bj[8];
#pragma unroll
  for (int j = 0; j < 8; ++j) bj[j] = bias[c0 + j];
#pragma unroll
  for (int i = 0; i < 8; ++i) {
    int r = row0 + r0 + i;
    if (r < N) {
      float s = scale[r];
      float o[8];
#pragma unroll
      for (int j = 0; j < 8; ++j) {
        float v = acc[i][j] * s + bj[j];
        o[j] = RELU ? fmaxf(v, 0.f) : v;
      }
      float4* op = (float4*)Out + (size_t)r * 32 + (c0 >> 2);
      op[0] = make_float4(o[0], o[1], o[2], o[3]);
      op[1] = make_float4(o[4], o[5], o[6], o[7]);
    }
  }
}

// ---- z GEMM: Z = A3 @ Wo[0:128] + A4 @ Wo[128:256]  (N x 64) ---------------
// 128-row x 64-col tile, 8x4 per thread, 8 K-chunks of 32 (A3 then A4).
__global__ __launch_bounds__(THREADS, 3)
void k_gemm_z(const float* __restrict__ A3, const float* __restrict__ A4,
              const float* __restrict__ Wo, float* __restrict__ Out, int N) {
  __shared__ float As[2][32 * 132];
  __shared__ float Ws[2][32 * 64];
  int t = threadIdx.x;
  int row0 = blockIdx.x * 128;
  int tx = t & 15, ty = t >> 4;
  int c0 = tx * 4, r0 = ty * 8;

  const float4* Wv = (const float4*)Wo;

  float4 la[4], lw[2];
  auto stage_load = [&](int chunk) {
    const float4* Av = (const float4*)((chunk < 4) ? A3 : A4);
    int kb = (chunk & 3) * 8;
#pragma unroll
    for (int j = 0; j < 4; ++j) {
      int i = t + j * 256;
      int r = i >> 3, kq = i & 7;
      la[j] = make_float4(0.f, 0.f, 0.f, 0.f);
      int gr = row0 + r;
      if (gr < N) la[j] = Av[(size_t)gr * 32 + kb + kq];
    }
#pragma unroll
    for (int j = 0; j < 2; ++j) {
      int i = t + j * 256;
      lw[j] = Wv[(size_t)(chunk * 32 + (i >> 4)) * 16 + (i & 15)];
    }
  };
  auto stage_write = [&](int buf) {
#pragma unroll
    for (int j = 0; j < 4; ++j) {
      int i = t + j * 256;
      int r = i >> 3, kq = i & 7;
      float* p = As[buf] + kq * 4 * 132 + r;
      p[0] = la[j].x; p[132] = la[j].y; p[264] = la[j].z; p[396] = la[j].w;
    }
    float4* Wsv = (float4*)Ws[buf];
#pragma unroll
    for (int j = 0; j < 2; ++j) Wsv[t + j * 256] = lw[j];
  };

  float acc[8][4] = {};
  stage_load(0);
  stage_write(0);
#pragma unroll 1
  for (int c = 0; c < 8; ++c) {
    __syncthreads();
    if (c < 7) stage_load(c + 1);
    const float* At = As[c & 1];
    const float* Wc = Ws[c & 1];
#pragma unroll 4
    for (int k = 0; k < 32; ++k) {
      float4 a0 = *(const float4*)&At[k * 132 + r0];
      float4 a1 = *(const float4*)&At[k * 132 + r0 + 4];
      float4 w = *(const float4*)&Wc[k * 64 + c0];
      float av[8] = {a0.x, a0.y, a0.z, a0.w, a1.x, a1.y, a1.z, a1.w};
      float wv[4] = {w.x, w.y, w.z, w.w};
#pragma unroll
      for (int ii = 0; ii < 8; ++ii)
#pragma unroll
        for (int jj = 0; jj < 4; ++jj)
          acc[ii][jj] += av[ii] * wv[jj];
    }
    if (c < 7) stage_write((c + 1) & 1);
  }

#pragma unroll
  for (int i = 0; i < 8; ++i) {
    int r = row0 + r0 + i;
    if (r < N) {
      ((float4*)Out)[(size_t)r * 16 + (c0 >> 2)] =
          make_float4(acc[i][0], acc[i][1], acc[i][2], acc[i][3]);
    }
  }
}

// ---------------------------------------------------------------------------
extern "C" void kernel_launch(void* const* d_in, const int* in_sizes, int n_in,
                              void* d_out, int out_size, void* d_ws, size_t ws_size,
                              hipStream_t stream) {
  const float* x    = (const float*)d_in[0];
  const int*   src  = (const int*)d_in[1];
  const int*   dst  = (const int*)d_in[2];
  const float* W1   = (const float*)d_in[3];
  const float* b1   = (const float*)d_in[4];
  const float* W2   = (const float*)d_in[5];
  const float* b2   = (const float*)d_in[6];
  const float* Wout = (const float*)d_in[7];
  const float* bout = (const float*)d_in[8];
  float* out = (float*)d_out;

  const int IN = 128;
  const int N = in_sizes[0] / IN;   // 100000
  const int E = in_sizes[1];        // 1600000

  char* p = (char*)d_ws;
  auto alloc = [&](size_t bytes) -> char* {
    char* r = p;
    p += (bytes + 255) & ~(size_t)255;
    return r;
  };
  float* buf1   = (float*)alloc((size_t)N * 128 * 4);  // aggA -> h1
  float* buf3   = (float*)alloc((size_t)N * 128 * 4);  // accB -> h2
  float* bufz   = (float*)alloc((size_t)N * 64 * 4);   // z = h1@Wo1 + h2@Wo2
  float* invo   = (float*)alloc((size_t)N * 4);
  float* invi   = (float*)alloc((size_t)N * 4);
  int* deg_o    = (int*)alloc((size_t)N * 4);
  int* deg_i    = (int*)alloc((size_t)N * 4);
  int* row_ptr  = (int*)alloc((size_t)(N + 1) * 4);
  int* cursor   = (int*)alloc((size_t)N * 4);
  int* bsums    = (int*)alloc(1024);
  int* boffs    = (int*)alloc(1024);
  int* csr_src  = (int*)alloc((size_t)E * 4);

  // ---- CSR build (XCD-sliced histogram + scatter) --------------------------
  hipMemsetAsync(deg_o, 0, (size_t)N * 4, stream);
  hipMemsetAsync(deg_i, 0, (size_t)N * 4, stream);
  k_degrees<<<2048, THREADS, 0, stream>>>(src, dst, deg_o, deg_i, N, E);
  k_inv<<<(N + THREADS - 1) / THREADS, THREADS, 0, stream>>>(deg_o, deg_i, invo, invi, N);
  int nb1 = (N + 1023) / 1024;
  k_scan1<<<nb1, THREADS, 0, stream>>>(deg_i, row_ptr, bsums, N);
  k_scan2<<<1, 256, 0, stream>>>(bsums, boffs, nb1);
  k_scan3<<<(N + THREADS - 1) / THREADS, THREADS, 0, stream>>>(row_ptr, deg_i, boffs, cursor, N, E);
  k_scatter<<<2048, THREADS, 0, stream>>>(src, dst, cursor, csr_src, N, E);

  const int aggGrid  = (N + (THREADS / 32) - 1) / (THREADS / 32);
  const int aggzGrid = (N + (THREADS / 16) - 1) / (THREADS / 16);
  const int gemmGrid = (N + 127) / 128;

  // ---- layer 1 -------------------------------------------------------------
  k_agg<<<aggGrid, THREADS, 0, stream>>>((const float4*)x, invo, row_ptr, csr_src,
                                         (float4*)buf1, N);
  k_gemm128<true><<<gemmGrid, THREADS, 0, stream>>>(buf1, W1, b1, invi, buf1, N);  // h1

  // ---- layer 2 -------------------------------------------------------------
  k_agg<<<aggGrid, THREADS, 0, stream>>>((const float4*)buf1, invo, row_ptr, csr_src,
                                         (float4*)buf3, N);
  k_gemm128<true><<<gemmGrid, THREADS, 0, stream>>>(buf3, W2, b2, invi, buf3, N);  // h2

  // ---- z = h1@Wo1 + h2@Wo2 then out = A@z + bout ---------------------------
  k_gemm_z<<<gemmGrid, THREADS, 0, stream>>>(buf1, buf3, Wout, bufz, N);
  k_agg_z<<<aggzGrid, THREADS, 0, stream>>>((const float4*)bufz, row_ptr, csr_src,
                                            bout, (float4*)out, N);
}

// Round 4
// 666.112 us; speedup vs baseline: 1.5425x; 1.1947x over previous
//
#include <hip/hip_runtime.h>
#include <cstddef>
#include <cstdint>

// ---------------------------------------------------------------------------
// JKNet: h1 = relu((D_in^-1/2 A D_out^-1/2 x) @ W1 + b1)
//        h2 = relu((D_in^-1/2 A D_out^-1/2 h1) @ W2 + b2)
//        out = (A @ [h1|h2]) @ Wout + bout = A@(h1@Wo1 + h2@Wo2) + deg*bout... 
//        (bout added inside the final gather: out[v] = sum z[src] + bout)
// Aggregate-first refactor (SpMM commutes with dense GEMM).
// R3: CSR build WITHOUT per-edge global atomics (device atomics are resolved
//     memory-side on gfx950 -> ~40ns each; R2's k_degrees burned 100MB of
//     WRITE_SIZE on 800KB of counters). New build:
//       k_hist: [range x chunk x {dst,src}] blocks, LDS histogram (12800
//               counters), coalesced flush to hist[c][v].
//       k_redinv: deg_i / invi / invo by summing hist columns.
//       scan (unchanged) -> row_ptr.
//       k_chunkscan: hist[c][v] -> per-(chunk,node) scatter offsets in place.
//       k_csr: re-read chunk, rank via LDS atomic on range slice, write
//              csr_src. Writers of range r are blocks == r (mod 8) -> same
//              XCD -> csr region (820KB) coalesces in its private L2.
//     Only LDS atomics remain (random over 12800 counters -> conflict-free).
// ---------------------------------------------------------------------------

#define THREADS 256
#define RANGE 12800      // nodes per LDS histogram slice (51.2 KB)
#define CHUNKS 32        // edge chunks

__device__ __forceinline__ float4 f4_fma(const float4 v, const float w, float4 a) {
  a.x += v.x * w; a.y += v.y * w; a.z += v.z * w; a.w += v.w * w; return a;
}
__device__ __forceinline__ float4 f4_add(const float4 v, float4 a) {
  a.x += v.x; a.y += v.y; a.z += v.z; a.w += v.w; return a;
}

// ---- 2D histogram: hist[c][v] = #edges in chunk c with key==v ---------------
// grid = ranges * CHUNKS * 2; aid picks dst (histD) or src (histS).
__global__ __launch_bounds__(THREADS)
void k_hist(const int* __restrict__ dst, const int* __restrict__ src,
            int* __restrict__ histD, int* __restrict__ histS,
            int N, int E, int ranges) {
  __shared__ int h[RANGE];
  int aid = blockIdx.x & 1;
  int r = (blockIdx.x >> 1) % ranges;
  int c = (blockIdx.x >> 1) / ranges;
  const int* arr = aid ? src : dst;
  int* hist = aid ? histS : histD;
  int lo = r * RANGE;
  unsigned span = (unsigned)min(RANGE, N - lo);
  int t = threadIdx.x;
  for (int j = t; j < RANGE; j += THREADS) h[j] = 0;
  __syncthreads();

  int beg = (int)((long long)c * E / CHUNKS);
  int end = (int)((long long)(c + 1) * E / CHUNKS);
  int a = min(end, (beg + 3) & ~3);
  for (int i = beg + t; i < a; i += THREADS) {
    unsigned u = (unsigned)(arr[i] - lo);
    if (u < span) atomicAdd(&h[u], 1);
  }
  for (int i4 = a + t * 4; i4 + 3 < end; i4 += THREADS * 4) {
    int4 v = *(const int4*)(arr + i4);
    unsigned u0 = (unsigned)(v.x - lo), u1 = (unsigned)(v.y - lo);
    unsigned u2 = (unsigned)(v.z - lo), u3 = (unsigned)(v.w - lo);
    if (u0 < span) atomicAdd(&h[u0], 1);
    if (u1 < span) atomicAdd(&h[u1], 1);
    if (u2 < span) atomicAdd(&h[u2], 1);
    if (u3 < span) atomicAdd(&h[u3], 1);
  }
  int tail = a + ((end - a) & ~3);
  for (int i = tail + t; i < end; i += THREADS) {
    unsigned u = (unsigned)(arr[i] - lo);
    if (u < span) atomicAdd(&h[u], 1);
  }
  __syncthreads();
  for (int j = t; j < (int)span; j += THREADS) hist[(size_t)c * N + lo + j] = h[j];
}

// ---- reduce hist columns -> deg_i, invi, invo ------------------------------
__global__ void k_redinv(const int* __restrict__ histD, const int* __restrict__ histS,
                         int* __restrict__ deg_i, float* __restrict__ inv_in,
                         float* __restrict__ inv_out, int N) {
  int v = blockIdx.x * blockDim.x + threadIdx.x;
  if (v >= N) return;
  int sD = 0, sS = 0;
#pragma unroll
  for (int c = 0; c < CHUNKS; ++c) {
    sD += histD[(size_t)c * N + v];
    sS += histS[(size_t)c * N + v];
  }
  deg_i[v] = sD;
  inv_in[v]  = rsqrtf((float)max(sD, 1));
  inv_out[v] = rsqrtf((float)max(sS, 1));
}

// ---- exclusive scan of deg_i -> row_ptr (3 kernels, chunk=1024) ------------
__global__ void k_scan1(const int* __restrict__ deg, int* __restrict__ incl,
                        int* __restrict__ bsums, int N) {
  __shared__ int sd[1024];
  int base = blockIdx.x * 1024;
  for (int j = threadIdx.x; j < 1024; j += THREADS) sd[j] = (base + j < N) ? deg[base + j] : 0;
  __syncthreads();
  for (int off = 1; off < 1024; off <<= 1) {
    int v[4];
#pragma unroll
    for (int k = 0; k < 4; ++k) { int j = threadIdx.x + k * THREADS; v[k] = (j >= off) ? sd[j - off] : 0; }
    __syncthreads();
#pragma unroll
    for (int k = 0; k < 4; ++k) { int j = threadIdx.x + k * THREADS; sd[j] += v[k]; }
    __syncthreads();
  }
  for (int j = threadIdx.x; j < 1024; j += THREADS) if (base + j < N) incl[base + j] = sd[j];
  if (threadIdx.x == 0) bsums[blockIdx.x] = sd[1023];
}

__global__ void k_scan2(const int* __restrict__ bsums, int* __restrict__ boffs, int nb) {
  __shared__ int sd[256];
  int t = threadIdx.x;
  sd[t] = (t < nb) ? bsums[t] : 0;
  __syncthreads();
  for (int off = 1; off < 256; off <<= 1) {
    int v = (t >= off) ? sd[t - off] : 0;
    __syncthreads();
    sd[t] += v;
    __syncthreads();
  }
  if (t < nb) boffs[t] = (t == 0) ? 0 : sd[t - 1];
}

__global__ void k_scan3(int* __restrict__ incl_rowptr, const int* __restrict__ deg,
                        const int* __restrict__ boffs, int N, int E) {
  int i = blockIdx.x * blockDim.x + threadIdx.x;
  if (i < N) incl_rowptr[i] = incl_rowptr[i] - deg[i] + boffs[i >> 10];
  if (i == 0) incl_rowptr[N] = E;
}

// ---- chunk-scan: histD[c][v] -> scatter offset base row_ptr[v]+prefix ------
__global__ void k_chunkscan(int* __restrict__ histD, const int* __restrict__ row_ptr, int N) {
  int v = blockIdx.x * blockDim.x + threadIdx.x;
  if (v >= N) return;
  int run = row_ptr[v];
#pragma unroll
  for (int c = 0; c < CHUNKS; ++c) {
    size_t idx = (size_t)c * N + v;
    int t = histD[idx];
    histD[idx] = run;
    run += t;
  }
}

// ---- CSR fill: rank via LDS atomic on range slice of offsets ---------------
// grid = ranges * CHUNKS, block (r, c): r = blockIdx % ranges (XCD-affine).
__global__ __launch_bounds__(THREADS)
void k_csr(const int* __restrict__ dst, const int* __restrict__ src,
           const int* __restrict__ offs, int* __restrict__ csr_src,
           int N, int E, int ranges) {
  __shared__ int offL[RANGE];
  int r = blockIdx.x % ranges;
  int c = blockIdx.x / ranges;
  int lo = r * RANGE;
  unsigned span = (unsigned)min(RANGE, N - lo);
  int t = threadIdx.x;
  for (int j = t; j < (int)span; j += THREADS) offL[j] = offs[(size_t)c * N + lo + j];
  __syncthreads();

  int beg = (int)((long long)c * E / CHUNKS);
  int end = (int)((long long)(c + 1) * E / CHUNKS);
  int a = min(end, (beg + 3) & ~3);
  for (int i = beg + t; i < a; i += THREADS) {
    unsigned u = (unsigned)(dst[i] - lo);
    if (u < span) csr_src[atomicAdd(&offL[u], 1)] = src[i];
  }
  for (int i4 = a + t * 4; i4 + 3 < end; i4 += THREADS * 4) {
    int4 d = *(const int4*)(dst + i4);
    int4 s = *(const int4*)(src + i4);
    unsigned u0 = (unsigned)(d.x - lo), u1 = (unsigned)(d.y - lo);
    unsigned u2 = (unsigned)(d.z - lo), u3 = (unsigned)(d.w - lo);
    if (u0 < span) csr_src[atomicAdd(&offL[u0], 1)] = s.x;
    if (u1 < span) csr_src[atomicAdd(&offL[u1], 1)] = s.y;
    if (u2 < span) csr_src[atomicAdd(&offL[u2], 1)] = s.z;
    if (u3 < span) csr_src[atomicAdd(&offL[u3], 1)] = s.w;
  }
  int tail = a + ((end - a) & ~3);
  for (int i = tail + t; i < end; i += THREADS) {
    unsigned u = (unsigned)(dst[i] - lo);
    if (u < span) csr_src[atomicAdd(&offL[u], 1)] = src[i];
  }
}

// ---- CSR aggregation (128-wide): O1[v] = sum_{e:dst=v} H[src]*invout[src] --
__global__ __launch_bounds__(THREADS)
void k_agg(const float4* __restrict__ H, const float* __restrict__ inv_out,
           const int* __restrict__ row_ptr, const int* __restrict__ csr_src,
           float4* __restrict__ O1, int N) {
  int g = blockIdx.x * (THREADS / 32) + (threadIdx.x >> 5);
  int lane = threadIdx.x & 31;
  if (g >= N) return;
  int e = row_ptr[g], end = row_ptr[g + 1];
  float4 s1 = make_float4(0.f, 0.f, 0.f, 0.f);
  for (; e + 1 < end; e += 2) {
    int n0 = csr_src[e], n1 = csr_src[e + 1];
    float4 v0 = H[(size_t)n0 * 32 + lane];
    float4 v1 = H[(size_t)n1 * 32 + lane];
    float w0 = inv_out[n0], w1 = inv_out[n1];
    s1 = f4_fma(v0, w0, s1); s1 = f4_fma(v1, w1, s1);
  }
  if (e < end) {
    int n0 = csr_src[e];
    s1 = f4_fma(H[(size_t)n0 * 32 + lane], inv_out[n0], s1);
  }
  O1[(size_t)g * 32 + lane] = s1;
}

// ---- CSR aggregation (64-wide, unweighted, +bout): out = sum z[src] + bout -
__global__ __launch_bounds__(THREADS)
void k_agg_z(const float4* __restrict__ Z, const int* __restrict__ row_ptr,
             const int* __restrict__ csr_src, const float* __restrict__ bo,
             float4* __restrict__ Out, int N) {
  int g = blockIdx.x * (THREADS / 16) + (threadIdx.x >> 4);
  int lane = threadIdx.x & 15;
  if (g >= N) return;
  int e = row_ptr[g], end = row_ptr[g + 1];
  float4 s = ((const float4*)bo)[lane];
  for (; e + 1 < end; e += 2) {
    int n0 = csr_src[e], n1 = csr_src[e + 1];
    float4 v0 = Z[(size_t)n0 * 16 + lane];
    float4 v1 = Z[(size_t)n1 * 16 + lane];
    s = f4_add(v0, s); s = f4_add(v1, s);
  }
  if (e < end) s = f4_add(Z[(size_t)csr_src[e] * 16 + lane], s);
  Out[(size_t)g * 16 + lane] = s;
}

// ---- 128x128 GEMM, fused scale+bias+relu ----------------------------------
template <bool RELU>
__global__ __launch_bounds__(THREADS, 2)
void k_gemm128(const float* __restrict__ A, const float* __restrict__ W,
               const float* __restrict__ bias, const float* __restrict__ scale,
               float* __restrict__ Out, int N) {
  __shared__ float As[2][32 * 132];   // transposed: As[k][row], stride 132
  __shared__ float Ws[2][32 * 128];   // Ws[k][col]
  int t = threadIdx.x;
  int row0 = blockIdx.x * 128;
  int tx = t & 15, ty = t >> 4;
  int c0 = tx * 8, r0 = ty * 8;

  const float4* Av = (const float4*)A;
  const float4* Wv = (const float4*)W;

  float4 la[4], lw[4];
  auto stage_load = [&](int chunk) {
#pragma unroll
    for (int j = 0; j < 4; ++j) {
      int i = t + j * 256;
      int r = i >> 3, kq = i & 7;
      la[j] = make_float4(0.f, 0.f, 0.f, 0.f);
      int gr = row0 + r;
      if (gr < N) la[j] = Av[(size_t)gr * 32 + chunk * 8 + kq];
    }
#pragma unroll
    for (int j = 0; j < 4; ++j) {
      int i = t + j * 256;
      lw[j] = Wv[(size_t)(chunk * 32 + (i >> 5)) * 32 + (i & 31)];
    }
  };
  auto stage_write = [&](int buf) {
#pragma unroll
    for (int j = 0; j < 4; ++j) {
      int i = t + j * 256;
      int r = i >> 3, kq = i & 7;
      float* p = As[buf] + kq * 4 * 132 + r;
      p[0] = la[j].x; p[132] = la[j].y; p[264] = la[j].z; p[396] = la[j].w;
    }
    float4* Wsv = (float4*)Ws[buf];
#pragma unroll
    for (int j = 0; j < 4; ++j) Wsv[t + j * 256] = lw[j];
  };

  float acc[8][8] = {};
  stage_load(0);
  stage_write(0);
#pragma unroll 1
  for (int c = 0; c < 4; ++c) {
    __syncthreads();
    if (c < 3) stage_load(c + 1);
    const float* At = As[c & 1];
    const float* Wc = Ws[c & 1];
#pragma unroll 4
    for (int k = 0; k < 32; ++k) {
      float4 a0 = *(const float4*)&At[k * 132 + r0];
      float4 a1 = *(const float4*)&At[k * 132 + r0 + 4];
      float4 w0 = *(const float4*)&Wc[k * 128 + c0];
      float4 w1 = *(const float4*)&Wc[k * 128 + c0 + 4];
      float av[8] = {a0.x, a0.y, a0.z, a0.w, a1.x, a1.y, a1.z, a1.w};
      float wv[8] = {w0.x, w0.y, w0.z, w0.w, w1.x, w1.y, w1.z, w1.w};
#pragma unroll
      for (int ii = 0; ii < 8; ++ii)
#pragma unroll
        for (int jj = 0; jj < 8; ++jj)
          acc[ii][jj] += av[ii] * wv[jj];
    }
    if (c < 3) stage_write((c + 1) & 1);
  }

  float bj[8];
#pragma unroll
  for (int j = 0; j < 8; ++j) bj[j] = bias[c0 + j];
#pragma unroll
  for (int i = 0; i < 8; ++i) {
    int r = row0 + r0 + i;
    if (r < N) {
      float s = scale[r];
      float o[8];
#pragma unroll
      for (int j = 0; j < 8; ++j) {
        float v = acc[i][j] * s + bj[j];
        o[j] = RELU ? fmaxf(v, 0.f) : v;
      }
      float4* op = (float4*)Out + (size_t)r * 32 + (c0 >> 2);
      op[0] = make_float4(o[0], o[1], o[2], o[3]);
      op[1] = make_float4(o[4], o[5], o[6], o[7]);
    }
  }
}

// ---- z GEMM: Z = A3 @ Wo[0:128] + A4 @ Wo[128:256]  (N x 64) ---------------
__global__ __launch_bounds__(THREADS, 3)
void k_gemm_z(const float* __restrict__ A3, const float* __restrict__ A4,
              const float* __restrict__ Wo, float* __restrict__ Out, int N) {
  __shared__ float As[2][32 * 132];
  __shared__ float Ws[2][32 * 64];
  int t = threadIdx.x;
  int row0 = blockIdx.x * 128;
  int tx = t & 15, ty = t >> 4;
  int c0 = tx * 4, r0 = ty * 8;

  const float4* Wv = (const float4*)Wo;

  float4 la[4], lw[2];
  auto stage_load = [&](int chunk) {
    const float4* Av = (const float4*)((chunk < 4) ? A3 : A4);
    int kb = (chunk & 3) * 8;
#pragma unroll
    for (int j = 0; j < 4; ++j) {
      int i = t + j * 256;
      int r = i >> 3, kq = i & 7;
      la[j] = make_float4(0.f, 0.f, 0.f, 0.f);
      int gr = row0 + r;
      if (gr < N) la[j] = Av[(size_t)gr * 32 + kb + kq];
    }
#pragma unroll
    for (int j = 0; j < 2; ++j) {
      int i = t + j * 256;
      lw[j] = Wv[(size_t)(chunk * 32 + (i >> 4)) * 16 + (i & 15)];
    }
  };
  auto stage_write = [&](int buf) {
#pragma unroll
    for (int j = 0; j < 4; ++j) {
      int i = t + j * 256;
      int r = i >> 3, kq = i & 7;
      float* p = As[buf] + kq * 4 * 132 + r;
      p[0] = la[j].x; p[132] = la[j].y; p[264] = la[j].z; p[396] = la[j].w;
    }
    float4* Wsv = (float4*)Ws[buf];
#pragma unroll
    for (int j = 0; j < 2; ++j) Wsv[t + j * 256] = lw[j];
  };

  float acc[8][4] = {};
  stage_load(0);
  stage_write(0);
#pragma unroll 1
  for (int c = 0; c < 8; ++c) {
    __syncthreads();
    if (c < 7) stage_load(c + 1);
    const float* At = As[c & 1];
    const float* Wc = Ws[c & 1];
#pragma unroll 4
    for (int k = 0; k < 32; ++k) {
      float4 a0 = *(const float4*)&At[k * 132 + r0];
      float4 a1 = *(const float4*)&At[k * 132 + r0 + 4];
      float4 w = *(const float4*)&Wc[k * 64 + c0];
      float av[8] = {a0.x, a0.y, a0.z, a0.w, a1.x, a1.y, a1.z, a1.w};
      float wv[4] = {w.x, w.y, w.z, w.w};
#pragma unroll
      for (int ii = 0; ii < 8; ++ii)
#pragma unroll
        for (int jj = 0; jj < 4; ++jj)
          acc[ii][jj] += av[ii] * wv[jj];
    }
    if (c < 7) stage_write((c + 1) & 1);
  }

#pragma unroll
  for (int i = 0; i < 8; ++i) {
    int r = row0 + r0 + i;
    if (r < N) {
      ((float4*)Out)[(size_t)r * 16 + (c0 >> 2)] =
          make_float4(acc[i][0], acc[i][1], acc[i][2], acc[i][3]);
    }
  }
}

// ---------------------------------------------------------------------------
extern "C" void kernel_launch(void* const* d_in, const int* in_sizes, int n_in,
                              void* d_out, int out_size, void* d_ws, size_t ws_size,
                              hipStream_t stream) {
  const float* x    = (const float*)d_in[0];
  const int*   src  = (const int*)d_in[1];
  const int*   dst  = (const int*)d_in[2];
  const float* W1   = (const float*)d_in[3];
  const float* b1   = (const float*)d_in[4];
  const float* W2   = (const float*)d_in[5];
  const float* b2   = (const float*)d_in[6];
  const float* Wout = (const float*)d_in[7];
  const float* bout = (const float*)d_in[8];
  float* out = (float*)d_out;

  const int IN = 128;
  const int N = in_sizes[0] / IN;   // 100000
  const int E = in_sizes[1];        // 1600000
  const int ranges = (N + RANGE - 1) / RANGE;  // 8

  char* p = (char*)d_ws;
  auto alloc = [&](size_t bytes) -> char* {
    char* r = p;
    p += (bytes + 255) & ~(size_t)255;
    return r;
  };
  float* buf1   = (float*)alloc((size_t)N * 128 * 4);  // aggA -> h1
  float* buf3   = (float*)alloc((size_t)N * 128 * 4);  // accB -> h2
  float* bufz   = (float*)alloc((size_t)2 * CHUNKS * N * 4); // histD|histS, later z
  float* invo   = (float*)alloc((size_t)N * 4);
  float* invi   = (float*)alloc((size_t)N * 4);
  int* deg_i    = (int*)alloc((size_t)N * 4);
  int* row_ptr  = (int*)alloc((size_t)(N + 1) * 4);
  int* bsums    = (int*)alloc(1024);
  int* boffs    = (int*)alloc(1024);
  int* csr_src  = (int*)alloc((size_t)E * 4);

  // hist arrays alias the (so-far unused) z buffer: dead before k_gemm_z runs.
  int* histD = (int*)bufz;                       // [CHUNKS][N]
  int* histS = histD + (size_t)CHUNKS * N;       // [CHUNKS][N]

  // ---- CSR build: no global atomics ---------------------------------------
  k_hist<<<ranges * CHUNKS * 2, THREADS, 0, stream>>>(dst, src, histD, histS, N, E, ranges);
  k_redinv<<<(N + THREADS - 1) / THREADS, THREADS, 0, stream>>>(histD, histS, deg_i, invi, invo, N);
  int nb1 = (N + 1023) / 1024;
  k_scan1<<<nb1, THREADS, 0, stream>>>(deg_i, row_ptr, bsums, N);
  k_scan2<<<1, 256, 0, stream>>>(bsums, boffs, nb1);
  k_scan3<<<(N + THREADS - 1) / THREADS, THREADS, 0, stream>>>(row_ptr, deg_i, boffs, N, E);
  k_chunkscan<<<(N + THREADS - 1) / THREADS, THREADS, 0, stream>>>(histD, row_ptr, N);
  k_csr<<<ranges * CHUNKS, THREADS, 0, stream>>>(dst, src, histD, csr_src, N, E, ranges);

  const int aggGrid  = (N + (THREADS / 32) - 1) / (THREADS / 32);
  const int aggzGrid = (N + (THREADS / 16) - 1) / (THREADS / 16);
  const int gemmGrid = (N + 127) / 128;

  // ---- layer 1 -------------------------------------------------------------
  k_agg<<<aggGrid, THREADS, 0, stream>>>((const float4*)x, invo, row_ptr, csr_src,
                                         (float4*)buf1, N);
  k_gemm128<true><<<gemmGrid, THREADS, 0, stream>>>(buf1, W1, b1, invi, buf1, N);  // h1

  // ---- layer 2 -------------------------------------------------------------
  k_agg<<<aggGrid, THREADS, 0, stream>>>((const float4*)buf1, invo, row_ptr, csr_src,
                                         (float4*)buf3, N);
  k_gemm128<true><<<gemmGrid, THREADS, 0, stream>>>(buf3, W2, b2, invi, buf3, N);  // h2

  // ---- z = h1@Wo1 + h2@Wo2 then out = A@z + bout ---------------------------
  k_gemm_z<<<gemmGrid, THREADS, 0, stream>>>(buf1, buf3, Wout, bufz, N);
  k_agg_z<<<aggzGrid, THREADS, 0, stream>>>((const float4*)bufz, row_ptr, csr_src,
                                            bout, (float4*)out, N);
}